// Round 4
// baseline (2819.948 us; speedup 1.0000x reference)
//
#include <hip/hip_runtime.h>
#include <math.h>

#define NN 4096
#define QQ 1024
#define LDA 1032              // padded leading dim (16B-aligned rows)
#define AF (1025 * 1032)      // floats occupied by bordered matrix A (1025 rows)

// ---------------- stats: r = yt-yp; s[q] += r; c[q] += 1; rr = sum r^2 ----------------
__global__ void k_stats(const float* __restrict__ yt, const float* __restrict__ yp,
                        const int* __restrict__ idx, float* __restrict__ s,
                        int* __restrict__ c, float* __restrict__ scal) {
    int i = blockIdx.x * 256 + threadIdx.x;
    float r = yt[i] - yp[i];
    int q = idx[i];
    atomicAdd(&s[q], r);
    atomicAdd(&c[q], 1);
    float v = r * r;
    for (int o = 32; o > 0; o >>= 1) v += __shfl_down(v, o, 64);
    __shared__ float red[4];
    int lane = threadIdx.x & 63, wid = threadIdx.x >> 6;
    if (lane == 0) red[wid] = v;
    __syncthreads();
    if (threadIdx.x == 0) atomicAdd(&scal[0], red[0] + red[1] + red[2] + red[3]);
}

// ---------------- matvec: t = D s ; w = sqrt(c)*t ; sqc ; st = s.t ----------------
__global__ void k_matvec(const float* __restrict__ dist, const float* __restrict__ s,
                         const int* __restrict__ c, float* __restrict__ t,
                         float* __restrict__ w, float* __restrict__ sqc,
                         float* __restrict__ scal, const float* __restrict__ sbs) {
    int i = blockIdx.x;
    float sb0 = sbs[0];
    float inv2 = 1.0f / (2.0f * sbs[1]);
    const float* dr = dist + (size_t)i * QQ;
    float acc = 0.f;
    for (int j = threadIdx.x; j < QQ; j += 256)
        acc += __expf(-dr[j] * inv2) * s[j];
    for (int o = 32; o > 0; o >>= 1) acc += __shfl_down(acc, o, 64);
    __shared__ float red[4];
    int lane = threadIdx.x & 63, wid = threadIdx.x >> 6;
    if (lane == 0) red[wid] = acc;
    __syncthreads();
    if (threadIdx.x == 0) {
        float tot = (red[0] + red[1] + red[2] + red[3]) * sb0;
        t[i] = tot;
        float sq = sqrtf((float)c[i]);
        sqc[i] = sq;
        w[i] = sq * tot;
        atomicAdd(&scal[1], s[i] * tot);
    }
}

// ---------------- build bordered S: A[i][j] = I + inv_se*sqc_i*sqc_j*D_ij; row QQ = w ----------------
__global__ void k_build(const float* __restrict__ dist, const float* __restrict__ sqc,
                        const float* __restrict__ w, float* __restrict__ A,
                        const float* __restrict__ se_p, const float* __restrict__ sbs) {
    int i = blockIdx.x;  // 0..1024
    if (i == QQ) {
        for (int j = threadIdx.x; j < QQ; j += 256) A[(size_t)QQ * LDA + j] = w[j];
        return;
    }
    float sb0 = sbs[0];
    float inv2 = 1.0f / (2.0f * sbs[1]);
    float inv_se = 1.0f / se_p[0];
    float qi = sqc[i] * inv_se * sb0;
    const float* dr = dist + (size_t)i * QQ;
    float* ar = A + (size_t)i * LDA;
    for (int j = threadIdx.x; j < QQ; j += 256)
        ar[j] = ((i == j) ? 1.0f : 0.0f) + qi * sqc[j] * __expf(-dr[j] * inv2);
}

// ======== template-unrolled potrf helpers: every index compile-time constant ========
// Rank-1 update: x[M] -= l_self * L[M][K], with L[M][K] fetched by constexpr-lane shuffle.
template<int K, int M>
struct PUpd {
    static __device__ __forceinline__ void run(float (&x)[64], float l) {
        if constexpr (M < 64) {
            x[M] = fmaf(-l, __shfl(l, M, 64), x[M]);
            PUpd<K, M + 1>::run(x, l);
        }
    }
};
template<int K>
struct PStep {
    static __device__ __forceinline__ void run(float (&x)[64], int j) {
        if constexpr (K < 64) {
            float diag = __shfl(x[K], K, 64);
            float inv_ = rsqrtf(diag) * 0.f;  // placeholder never used
            (void)inv_;
            float s_ = sqrtf(diag);
            float r_ = 1.0f / s_;
            float l = (j == K) ? s_ : x[K] * r_;  // lanes j<K produce garbage, never consumed
            if (j >= K) x[K] = l;
            PUpd<K, K + 1>::run(x, l);
            PStep<K + 1>::run(x, j);
        }
    }
};

// ---------------- potrf of 64x64 diag block: 64 threads, register rows, shuffle column ----------------
// Thread j holds row j in x[64] (all indices constexpr via templates -> cannot spill to
// dynamically-indexed scratch). No LDS, no barriers: column broadcast via __shfl from
// constexpr lane. __launch_bounds__(64,2) caps VGPR at 256 (need ~100).
__global__ __launch_bounds__(64, 2) void k_potrf(float* __restrict__ A, int p) {
    int j = threadIdx.x;
    float* row = A + (size_t)(p * 64 + j) * LDA + p * 64;
    float x[64];
#pragma unroll
    for (int m4 = 0; m4 < 16; ++m4) {
        float4 v = ((const float4*)row)[m4];
        x[4 * m4 + 0] = v.x; x[4 * m4 + 1] = v.y;
        x[4 * m4 + 2] = v.z; x[4 * m4 + 3] = v.w;
    }
    PStep<0>::run(x, j);
#pragma unroll
    for (int m4 = 0; m4 < 16; ++m4)
        ((float4*)row)[m4] = make_float4(x[4 * m4], x[4 * m4 + 1],
                                         x[4 * m4 + 2], x[4 * m4 + 3]);
}

// ======== template-unrolled trsm helpers ========
template<int K, int M>
struct TAcc {
    static __device__ __forceinline__ void run(const float (&Lb)[64][65], const float (&x)[64],
                                               float& a0, float& a1) {
        if constexpr (M < K)     a0 = fmaf(-Lb[K][M], x[M], a0);
        if constexpr (M + 1 < K) a1 = fmaf(-Lb[K][M + 1], x[M + 1], a1);
        if constexpr (M + 2 < K) TAcc<K, M + 2>::run(Lb, x, a0, a1);
    }
};
template<int K>
struct TStep {
    static __device__ __forceinline__ void run(const float (&Lb)[64][65], const float (&dinv)[64],
                                               float (&x)[64]) {
        if constexpr (K < 64) {
            float a0 = x[K], a1 = 0.f;
            TAcc<K, 0>::run(Lb, x, a0, a1);
            x[K] = (a0 + a1) * dinv[K];
            TStep<K + 1>::run(Lb, dinv, x);
        }
    }
};

// ---------------- trsm: rows below panel (incl. bordered w-row): X * Lpp^T = A_panel ----------------
__global__ __launch_bounds__(64, 2) void k_trsm(float* __restrict__ A, int p) {
    __shared__ float Lb[64][65];
    __shared__ float dinv[64];
    int t = threadIdx.x;  // 64 threads
    const float* db = A + (size_t)(p * 64) * (LDA + 1);
    for (int i = 0; i < 64; ++i) Lb[i][t] = db[(size_t)i * LDA + t];
    dinv[t] = 1.0f / Lb[t][t];
    __syncthreads();
    int r = (p + 1) * 64 + blockIdx.x * 64 + t;
    if (r <= QQ) {
        float* ar = A + (size_t)r * LDA + p * 64;
        float x[64];
#pragma unroll
        for (int jj = 0; jj < 16; ++jj) {
            float4 v = ((const float4*)ar)[jj];
            x[4 * jj] = v.x; x[4 * jj + 1] = v.y; x[4 * jj + 2] = v.z; x[4 * jj + 3] = v.w;
        }
        TStep<0>::run(Lb, dinv, x);
#pragma unroll
        for (int jj = 0; jj < 16; ++jj)
            ((float4*)ar)[jj] = make_float4(x[4 * jj], x[4 * jj + 1], x[4 * jj + 2], x[4 * jj + 3]);
    }
}

// ---------------- syrk: trailing update A -= P * P^T (lower tiles only) ----------------
__global__ void k_syrk(float* __restrict__ A, int p) {
    int t0 = (p + 1) * 64;
    int r0 = t0 + blockIdx.y * 32;
    int c0 = t0 + blockIdx.x * 32;
    if (c0 > r0 + 31) return;  // uniform: tile entirely above diagonal
    __shared__ float Pr[32][65];
    __shared__ float Pc[32][65];
    int t = threadIdx.x;  // 256
    int pc0 = p * 64;
    for (int idx2 = t; idx2 < 2048; idx2 += 256) {
        int i = idx2 >> 6, k = idx2 & 63;
        int rr = r0 + i;
        Pr[i][k] = (rr <= QQ) ? A[(size_t)rr * LDA + pc0 + k] : 0.f;
        int cc = c0 + i;
        Pc[i][k] = (cc < QQ) ? A[(size_t)cc * LDA + pc0 + k] : 0.f;
    }
    __syncthreads();
    int tx = t & 31, ty = t >> 5;  // ty 0..7
    float acc[4] = {0.f, 0.f, 0.f, 0.f};
#pragma unroll 4
    for (int k = 0; k < 64; ++k) {
        float b = Pc[tx][k];
#pragma unroll
        for (int ii = 0; ii < 4; ++ii)
            acc[ii] = fmaf(Pr[ty + 8 * ii][k], b, acc[ii]);
    }
#pragma unroll
    for (int ii = 0; ii < 4; ++ii) {
        int rr = r0 + ty + 8 * ii, cc = c0 + tx;
        if (rr <= QQ && cc < QQ)
            A[(size_t)rr * LDA + cc] -= acc[ii];
    }
}

// ---------------- finalize: logdet from diag, yy from bordered row, combine ----------------
__global__ void k_final(const float* __restrict__ A, const float* __restrict__ scal,
                        const float* __restrict__ se_p, float* __restrict__ out) {
    int i = threadIdx.x;  // 1024
    float v1 = 2.0f * __logf(A[(size_t)i * LDA + i]);
    float yv = A[(size_t)QQ * LDA + i];
    float v2 = yv * yv;
    for (int o = 32; o > 0; o >>= 1) {
        v1 += __shfl_down(v1, o, 64);
        v2 += __shfl_down(v2, o, 64);
    }
    __shared__ float r1[16], r2[16];
    int lane = i & 63, wid = i >> 6;
    if (lane == 0) { r1[wid] = v1; r2[wid] = v2; }
    __syncthreads();
    if (i == 0) {
        float ld = 0.f, yy = 0.f;
        for (int k = 0; k < 16; ++k) { ld += r1[k]; yy += r2[k]; }
        float se = se_p[0], inv = 1.0f / se;
        float rr = scal[0], st = scal[1];
        float quad = rr * inv - inv * inv * (st - inv * yy);
        float logdetV = (float)NN * __logf(se) + ld;
        out[0] = 0.5f * (float)NN * 1.8378770664093453f + 0.5f * logdetV + 0.5f * quad;
    }
}

extern "C" void kernel_launch(void* const* d_in, const int* in_sizes, int n_in,
                              void* d_out, int out_size, void* d_ws, size_t ws_size,
                              hipStream_t stream) {
    const float* yt   = (const float*)d_in[0];
    const float* yp   = (const float*)d_in[1];
    const int*   idx  = (const int*)d_in[2];
    const float* dist = (const float*)d_in[3];
    const float* se   = (const float*)d_in[4];
    const float* sbs  = (const float*)d_in[5];
    float* out = (float*)d_out;

    float* W    = (float*)d_ws;
    float* A    = W;                      // 1025 x LDA
    int*   c    = (int*)(W + AF);         // 1024
    float* s    = W + AF + 1024;          // 1024
    float* scal = W + AF + 2048;          // rr, st
    float* t    = scal + 2;               // 1024
    float* w    = t + 1024;               // 1024
    float* sqc  = w + 1024;               // 1024

    // zero accumulators: c(1024 int) + s(1024 f) + scal(2 f), contiguous
    hipMemsetAsync(c, 0, (1024 + 1024 + 2) * sizeof(float), stream);

    k_stats<<<dim3(NN / 256), dim3(256), 0, stream>>>(yt, yp, idx, s, c, scal);
    k_matvec<<<dim3(QQ), dim3(256), 0, stream>>>(dist, s, c, t, w, sqc, scal, sbs);
    k_build<<<dim3(QQ + 1), dim3(256), 0, stream>>>(dist, sqc, w, A, se, sbs);

    for (int p = 0; p < 16; ++p) {
        k_potrf<<<dim3(1), dim3(64), 0, stream>>>(A, p);
        int rows = (QQ + 1) - (p + 1) * 64;
        k_trsm<<<dim3((rows + 63) / 64), dim3(64), 0, stream>>>(A, p);
        int cols = QQ - (p + 1) * 64;
        if (cols > 0) {
            dim3 g((cols + 31) / 32, (rows + 31) / 32);
            k_syrk<<<g, dim3(256), 0, stream>>>(A, p);
        }
    }
    k_final<<<dim3(1), dim3(1024), 0, stream>>>(A, scal, se, out);
}

// Round 5
// 1193.061 us; speedup vs baseline: 2.3636x; 2.3636x over previous
//
#include <hip/hip_runtime.h>
#include <math.h>

#define NN 4096
#define QQ 1024
#define LDA 1032              // padded leading dim (16B-aligned rows)
#define AF (1025 * 1032)      // floats occupied by bordered matrix A (1025 rows)

// ---------------- stats: r = yt-yp; s[q] += r; c[q] += 1; rr = sum r^2 ----------------
__global__ void k_stats(const float* __restrict__ yt, const float* __restrict__ yp,
                        const int* __restrict__ idx, float* __restrict__ s,
                        int* __restrict__ c, float* __restrict__ scal) {
    int i = blockIdx.x * 256 + threadIdx.x;
    float r = yt[i] - yp[i];
    int q = idx[i];
    atomicAdd(&s[q], r);
    atomicAdd(&c[q], 1);
    float v = r * r;
    for (int o = 32; o > 0; o >>= 1) v += __shfl_down(v, o, 64);
    __shared__ float red[4];
    int lane = threadIdx.x & 63, wid = threadIdx.x >> 6;
    if (lane == 0) red[wid] = v;
    __syncthreads();
    if (threadIdx.x == 0) atomicAdd(&scal[0], red[0] + red[1] + red[2] + red[3]);
}

// ---------------- matvec: t = D s ; w = sqrt(c)*t ; sqc ; st = s.t ----------------
__global__ void k_matvec(const float* __restrict__ dist, const float* __restrict__ s,
                         const int* __restrict__ c, float* __restrict__ t,
                         float* __restrict__ w, float* __restrict__ sqc,
                         float* __restrict__ scal, const float* __restrict__ sbs) {
    int i = blockIdx.x;
    float sb0 = sbs[0];
    float inv2 = 1.0f / (2.0f * sbs[1]);
    const float* dr = dist + (size_t)i * QQ;
    float acc = 0.f;
    for (int j = threadIdx.x; j < QQ; j += 256)
        acc += __expf(-dr[j] * inv2) * s[j];
    for (int o = 32; o > 0; o >>= 1) acc += __shfl_down(acc, o, 64);
    __shared__ float red[4];
    int lane = threadIdx.x & 63, wid = threadIdx.x >> 6;
    if (lane == 0) red[wid] = acc;
    __syncthreads();
    if (threadIdx.x == 0) {
        float tot = (red[0] + red[1] + red[2] + red[3]) * sb0;
        t[i] = tot;
        float sq = sqrtf((float)c[i]);
        sqc[i] = sq;
        w[i] = sq * tot;
        atomicAdd(&scal[1], s[i] * tot);
    }
}

// ---------------- build bordered S: A[i][j] = I + inv_se*sqc_i*sqc_j*D_ij; row QQ = w ----------------
__global__ void k_build(const float* __restrict__ dist, const float* __restrict__ sqc,
                        const float* __restrict__ w, float* __restrict__ A,
                        const float* __restrict__ se_p, const float* __restrict__ sbs) {
    int i = blockIdx.x;  // 0..1024
    if (i == QQ) {
        for (int j = threadIdx.x; j < QQ; j += 256) A[(size_t)QQ * LDA + j] = w[j];
        return;
    }
    float sb0 = sbs[0];
    float inv2 = 1.0f / (2.0f * sbs[1]);
    float inv_se = 1.0f / se_p[0];
    float qi = sqc[i] * inv_se * sb0;
    const float* dr = dist + (size_t)i * QQ;
    float* ar = A + (size_t)i * LDA;
    for (int j = threadIdx.x; j < QQ; j += 256)
        ar[j] = ((i == j) ? 1.0f : 0.0f) + qi * sqc[j] * __expf(-dr[j] * inv2);
}

// ---------------- potrf of 64x64 diag block ----------------
// 256 threads. Thread (i = tid&63, q = tid>>6) owns 16 floats of row i
// (cols 16q..16q+15) in x[16] — only constant indices, so the allocator
// CANNOT spill it to dynamically-indexed scratch (R2/R3/R4 all lost to
// spills of 64-float arrays). Column k broadcast via double-buffered LDS,
// re-read as broadcast float4s. x[k&15] extracted by cndmask select chain.
__global__ __launch_bounds__(256) void k_potrf(float* __restrict__ A, int p) {
    __shared__ float col[2][64];
    __shared__ float dg[2];
    int tid = threadIdx.x;
    int i = tid & 63;       // row
    int q = tid >> 6;       // column chunk (16 cols)
    float* base = A + (size_t)(p * 64 + i) * LDA + p * 64 + 16 * q;
    float x[16];
#pragma unroll
    for (int m4 = 0; m4 < 4; ++m4) {
        float4 v = ((const float4*)base)[m4];
        x[4 * m4 + 0] = v.x; x[4 * m4 + 1] = v.y;
        x[4 * m4 + 2] = v.z; x[4 * m4 + 3] = v.w;
    }
    for (int k = 0; k < 64; ++k) {
        int qk = k >> 4, ck = k & 15, b = k & 1;
        // xk = x[ck] via constant-index select chain
        float xk = x[0];
#pragma unroll
        for (int m = 1; m < 16; ++m) xk = (ck == m) ? x[m] : xk;
        if (q == qk && i == k) dg[b] = xk;
        __syncthreads();
        float s_ = sqrtf(dg[b]);
        float rinv = 1.0f / s_;
        if (q == qk && i >= k) {
            float l = (i == k) ? s_ : xk * rinv;
            col[b][i] = l;
#pragma unroll
            for (int m = 0; m < 16; ++m) if (m == ck) x[m] = l;
        }
        __syncthreads();
        if (i > k) {
            float li = col[b][i];
            float cl[16];
#pragma unroll
            for (int m4 = 0; m4 < 4; ++m4) {
                float4 v = ((const float4*)(&col[b][16 * q]))[m4];  // broadcast read
                cl[4 * m4 + 0] = v.x; cl[4 * m4 + 1] = v.y;
                cl[4 * m4 + 2] = v.z; cl[4 * m4 + 3] = v.w;
            }
#pragma unroll
            for (int m = 0; m < 16; ++m)
                if (16 * q + m > k) x[m] = fmaf(-li, cl[m], x[m]);
        }
    }
#pragma unroll
    for (int m4 = 0; m4 < 4; ++m4)
        ((float4*)base)[m4] = make_float4(x[4 * m4 + 0], x[4 * m4 + 1],
                                          x[4 * m4 + 2], x[4 * m4 + 3]);
}

// ======== template-unrolled trsm helpers ========
template<int K, int M>
struct TAcc {
    static __device__ __forceinline__ void run(const float (&Lb)[64][65], const float (&x)[64],
                                               float& a0, float& a1) {
        if constexpr (M < K)     a0 = fmaf(-Lb[K][M], x[M], a0);
        if constexpr (M + 1 < K) a1 = fmaf(-Lb[K][M + 1], x[M + 1], a1);
        if constexpr (M + 2 < K) TAcc<K, M + 2>::run(Lb, x, a0, a1);
    }
};
template<int K>
struct TStep {
    static __device__ __forceinline__ void run(const float (&Lb)[64][65], const float (&dinv)[64],
                                               float (&x)[64]) {
        if constexpr (K < 64) {
            float a0 = x[K], a1 = 0.f;
            TAcc<K, 0>::run(Lb, x, a0, a1);
            x[K] = (a0 + a1) * dinv[K];
            TStep<K + 1>::run(Lb, dinv, x);
        }
    }
};

// ---------------- trsm: rows below panel (incl. bordered w-row): X * Lpp^T = A_panel ----------------
__global__ __launch_bounds__(64, 2) void k_trsm(float* __restrict__ A, int p) {
    __shared__ float Lb[64][65];
    __shared__ float dinv[64];
    int t = threadIdx.x;  // 64 threads
    const float* db = A + (size_t)(p * 64) * (LDA + 1);
    for (int i = 0; i < 64; ++i) Lb[i][t] = db[(size_t)i * LDA + t];
    dinv[t] = 1.0f / Lb[t][t];
    __syncthreads();
    int r = (p + 1) * 64 + blockIdx.x * 64 + t;
    if (r <= QQ) {
        float* ar = A + (size_t)r * LDA + p * 64;
        float x[64];
#pragma unroll
        for (int jj = 0; jj < 16; ++jj) {
            float4 v = ((const float4*)ar)[jj];
            x[4 * jj] = v.x; x[4 * jj + 1] = v.y; x[4 * jj + 2] = v.z; x[4 * jj + 3] = v.w;
        }
        TStep<0>::run(Lb, dinv, x);
#pragma unroll
        for (int jj = 0; jj < 16; ++jj)
            ((float4*)ar)[jj] = make_float4(x[4 * jj], x[4 * jj + 1], x[4 * jj + 2], x[4 * jj + 3]);
    }
}

// ---------------- syrk: trailing update A -= P * P^T (lower tiles only) ----------------
__global__ void k_syrk(float* __restrict__ A, int p) {
    int t0 = (p + 1) * 64;
    int r0 = t0 + blockIdx.y * 32;
    int c0 = t0 + blockIdx.x * 32;
    if (c0 > r0 + 31) return;  // uniform: tile entirely above diagonal
    __shared__ float Pr[32][65];
    __shared__ float Pc[32][65];
    int t = threadIdx.x;  // 256
    int pc0 = p * 64;
    for (int idx2 = t; idx2 < 2048; idx2 += 256) {
        int i = idx2 >> 6, k = idx2 & 63;
        int rr = r0 + i;
        Pr[i][k] = (rr <= QQ) ? A[(size_t)rr * LDA + pc0 + k] : 0.f;
        int cc = c0 + i;
        Pc[i][k] = (cc < QQ) ? A[(size_t)cc * LDA + pc0 + k] : 0.f;
    }
    __syncthreads();
    int tx = t & 31, ty = t >> 5;  // ty 0..7
    float acc[4] = {0.f, 0.f, 0.f, 0.f};
#pragma unroll 4
    for (int k = 0; k < 64; ++k) {
        float b = Pc[tx][k];
#pragma unroll
        for (int ii = 0; ii < 4; ++ii)
            acc[ii] = fmaf(Pr[ty + 8 * ii][k], b, acc[ii]);
    }
#pragma unroll
    for (int ii = 0; ii < 4; ++ii) {
        int rr = r0 + ty + 8 * ii, cc = c0 + tx;
        if (rr <= QQ && cc < QQ)
            A[(size_t)rr * LDA + cc] -= acc[ii];
    }
}

// ---------------- finalize: logdet from diag, yy from bordered row, combine ----------------
__global__ void k_final(const float* __restrict__ A, const float* __restrict__ scal,
                        const float* __restrict__ se_p, float* __restrict__ out) {
    int i = threadIdx.x;  // 1024
    float v1 = 2.0f * __logf(A[(size_t)i * LDA + i]);
    float yv = A[(size_t)QQ * LDA + i];
    float v2 = yv * yv;
    for (int o = 32; o > 0; o >>= 1) {
        v1 += __shfl_down(v1, o, 64);
        v2 += __shfl_down(v2, o, 64);
    }
    __shared__ float r1[16], r2[16];
    int lane = i & 63, wid = i >> 6;
    if (lane == 0) { r1[wid] = v1; r2[wid] = v2; }
    __syncthreads();
    if (i == 0) {
        float ld = 0.f, yy = 0.f;
        for (int k = 0; k < 16; ++k) { ld += r1[k]; yy += r2[k]; }
        float se = se_p[0], inv = 1.0f / se;
        float rr = scal[0], st = scal[1];
        float quad = rr * inv - inv * inv * (st - inv * yy);
        float logdetV = (float)NN * __logf(se) + ld;
        out[0] = 0.5f * (float)NN * 1.8378770664093453f + 0.5f * logdetV + 0.5f * quad;
    }
}

extern "C" void kernel_launch(void* const* d_in, const int* in_sizes, int n_in,
                              void* d_out, int out_size, void* d_ws, size_t ws_size,
                              hipStream_t stream) {
    const float* yt   = (const float*)d_in[0];
    const float* yp   = (const float*)d_in[1];
    const int*   idx  = (const int*)d_in[2];
    const float* dist = (const float*)d_in[3];
    const float* se   = (const float*)d_in[4];
    const float* sbs  = (const float*)d_in[5];
    float* out = (float*)d_out;

    float* W    = (float*)d_ws;
    float* A    = W;                      // 1025 x LDA
    int*   c    = (int*)(W + AF);         // 1024
    float* s    = W + AF + 1024;          // 1024
    float* scal = W + AF + 2048;          // rr, st
    float* t    = scal + 2;               // 1024
    float* w    = t + 1024;               // 1024
    float* sqc  = w + 1024;               // 1024

    // zero accumulators: c(1024 int) + s(1024 f) + scal(2 f), contiguous
    hipMemsetAsync(c, 0, (1024 + 1024 + 2) * sizeof(float), stream);

    k_stats<<<dim3(NN / 256), dim3(256), 0, stream>>>(yt, yp, idx, s, c, scal);
    k_matvec<<<dim3(QQ), dim3(256), 0, stream>>>(dist, s, c, t, w, sqc, scal, sbs);
    k_build<<<dim3(QQ + 1), dim3(256), 0, stream>>>(dist, sqc, w, A, se, sbs);

    for (int p = 0; p < 16; ++p) {
        k_potrf<<<dim3(1), dim3(256), 0, stream>>>(A, p);
        int rows = (QQ + 1) - (p + 1) * 64;
        k_trsm<<<dim3((rows + 63) / 64), dim3(64), 0, stream>>>(A, p);
        int cols = QQ - (p + 1) * 64;
        if (cols > 0) {
            dim3 g((cols + 31) / 32, (rows + 31) / 32);
            k_syrk<<<g, dim3(256), 0, stream>>>(A, p);
        }
    }
    k_final<<<dim3(1), dim3(1024), 0, stream>>>(A, scal, se, out);
}

// Round 6
// 796.948 us; speedup vs baseline: 3.5384x; 1.4970x over previous
//
#include <hip/hip_runtime.h>
#include <math.h>

#define NN 4096
#define QQ 1024
#define LDA 1032              // padded leading dim (16B-aligned rows)
#define AF (1025 * 1032)      // floats occupied by bordered matrix A (1025 rows)

// ---------------- stats: r = yt-yp; s[q] += r; c[q] += 1; rr = sum r^2 ----------------
__global__ void k_stats(const float* __restrict__ yt, const float* __restrict__ yp,
                        const int* __restrict__ idx, float* __restrict__ s,
                        int* __restrict__ c, float* __restrict__ scal) {
    int i = blockIdx.x * 256 + threadIdx.x;
    float r = yt[i] - yp[i];
    int q = idx[i];
    atomicAdd(&s[q], r);
    atomicAdd(&c[q], 1);
    float v = r * r;
    for (int o = 32; o > 0; o >>= 1) v += __shfl_down(v, o, 64);
    __shared__ float red[4];
    int lane = threadIdx.x & 63, wid = threadIdx.x >> 6;
    if (lane == 0) red[wid] = v;
    __syncthreads();
    if (threadIdx.x == 0) atomicAdd(&scal[0], red[0] + red[1] + red[2] + red[3]);
}

// ---------------- matvec: t = D s ; w = sqrt(c)*t ; sqc ; st = s.t ----------------
__global__ void k_matvec(const float* __restrict__ dist, const float* __restrict__ s,
                         const int* __restrict__ c, float* __restrict__ t,
                         float* __restrict__ w, float* __restrict__ sqc,
                         float* __restrict__ scal, const float* __restrict__ sbs) {
    int i = blockIdx.x;
    float sb0 = sbs[0];
    float inv2 = 1.0f / (2.0f * sbs[1]);
    const float* dr = dist + (size_t)i * QQ;
    float acc = 0.f;
    for (int j = threadIdx.x; j < QQ; j += 256)
        acc += __expf(-dr[j] * inv2) * s[j];
    for (int o = 32; o > 0; o >>= 1) acc += __shfl_down(acc, o, 64);
    __shared__ float red[4];
    int lane = threadIdx.x & 63, wid = threadIdx.x >> 6;
    if (lane == 0) red[wid] = acc;
    __syncthreads();
    if (threadIdx.x == 0) {
        float tot = (red[0] + red[1] + red[2] + red[3]) * sb0;
        t[i] = tot;
        float sq = sqrtf((float)c[i]);
        sqc[i] = sq;
        w[i] = sq * tot;
        atomicAdd(&scal[1], s[i] * tot);
    }
}

// ---------------- build bordered S: A[i][j] = I + inv_se*sqc_i*sqc_j*D_ij; row QQ = w ----------------
__global__ void k_build(const float* __restrict__ dist, const float* __restrict__ sqc,
                        const float* __restrict__ w, float* __restrict__ A,
                        const float* __restrict__ se_p, const float* __restrict__ sbs) {
    int i = blockIdx.x;  // 0..1024
    if (i == QQ) {
        for (int j = threadIdx.x; j < QQ; j += 256) A[(size_t)QQ * LDA + j] = w[j];
        return;
    }
    float sb0 = sbs[0];
    float inv2 = 1.0f / (2.0f * sbs[1]);
    float inv_se = 1.0f / se_p[0];
    float qi = sqc[i] * inv_se * sb0;
    const float* dr = dist + (size_t)i * QQ;
    float* ar = A + (size_t)i * LDA;
    for (int j = threadIdx.x; j < QQ; j += 256)
        ar[j] = ((i == j) ? 1.0f : 0.0f) + qi * sqc[j] * __expf(-dr[j] * inv2);
}

// ---------------- potrf of 64x64 diag block ----------------
// 256 threads; thread (i = tid&63, q = tid>>6) owns x[16] = row i, cols 16q..16q+15.
// k-loop fully unrolled as qk x ck so every x[] index is a compile-time constant
// (no spill, no select chain). Diagonal broadcast is IN-WAVE (chunk qk's 64 rows
// are exactly one wave) via __shfl with constexpr lane -> v_readlane; the wave
// publishes the finished, already-scaled column in one LDS write. ONE barrier
// per step (double-buffered col). R5 had 2 barriers + 3 LDS round-trips/step.
__global__ __launch_bounds__(256) void k_potrf(float* __restrict__ A, int p) {
    __shared__ float col[2][64];
    int tid = threadIdx.x;
    int i = tid & 63;       // row
    int q = tid >> 6;       // column chunk (16 cols)
    float* base = A + (size_t)(p * 64 + i) * LDA + p * 64 + 16 * q;
    float x[16];
#pragma unroll
    for (int m4 = 0; m4 < 4; ++m4) {
        float4 v = ((const float4*)base)[m4];
        x[4 * m4 + 0] = v.x; x[4 * m4 + 1] = v.y;
        x[4 * m4 + 2] = v.z; x[4 * m4 + 3] = v.w;
    }
#pragma unroll
    for (int qk = 0; qk < 4; ++qk) {
#pragma unroll
        for (int ck = 0; ck < 16; ++ck) {
            const int k = qk * 16 + ck;
            const int b = k & 1;
            if (q == qk) {                       // wave-uniform: only wave qk works here
                float xk = x[ck];                // constant index
                float diag = __shfl(xk, k, 64);  // constexpr lane -> readlane broadcast
                float rs = rsqrtf(diag);
                float l = (i == k) ? diag * rs : xk * rs;
                if (i >= k) x[ck] = l;
                col[b][i] = l;                   // i<k lanes publish garbage, never read
            }
            __syncthreads();
            if (16 * q + 15 > k) {               // wave-uniform: skip chunks left of col k
                if (i > k) {
                    float li = col[b][i];
                    float cl[16];
#pragma unroll
                    for (int m4 = 0; m4 < 4; ++m4) {
                        float4 v = ((const float4*)(&col[b][16 * q]))[m4];  // broadcast read
                        cl[4 * m4 + 0] = v.x; cl[4 * m4 + 1] = v.y;
                        cl[4 * m4 + 2] = v.z; cl[4 * m4 + 3] = v.w;
                    }
#pragma unroll
                    for (int m = 0; m < 16; ++m)
                        if (16 * q + m > k) x[m] = fmaf(-li, cl[m], x[m]);
                }
            }
        }
    }
#pragma unroll
    for (int m4 = 0; m4 < 4; ++m4)
        ((float4*)base)[m4] = make_float4(x[4 * m4 + 0], x[4 * m4 + 1],
                                          x[4 * m4 + 2], x[4 * m4 + 3]);
}

// ======== template-unrolled trsm helpers ========
template<int K, int M>
struct TAcc {
    static __device__ __forceinline__ void run(const float (&Lb)[64][65], const float (&x)[64],
                                               float& a0, float& a1) {
        if constexpr (M < K)     a0 = fmaf(-Lb[K][M], x[M], a0);
        if constexpr (M + 1 < K) a1 = fmaf(-Lb[K][M + 1], x[M + 1], a1);
        if constexpr (M + 2 < K) TAcc<K, M + 2>::run(Lb, x, a0, a1);
    }
};
template<int K>
struct TStep {
    static __device__ __forceinline__ void run(const float (&Lb)[64][65], const float (&dinv)[64],
                                               float (&x)[64]) {
        if constexpr (K < 64) {
            float a0 = x[K], a1 = 0.f;
            TAcc<K, 0>::run(Lb, x, a0, a1);
            x[K] = (a0 + a1) * dinv[K];
            TStep<K + 1>::run(Lb, dinv, x);
        }
    }
};

// ---------------- trsm: rows below panel (incl. bordered w-row): X * Lpp^T = A_panel ----------------
__global__ __launch_bounds__(64, 2) void k_trsm(float* __restrict__ A, int p) {
    __shared__ float Lb[64][65];
    __shared__ float dinv[64];
    int t = threadIdx.x;  // 64 threads
    const float* db = A + (size_t)(p * 64) * (LDA + 1);
    for (int i = 0; i < 64; ++i) Lb[i][t] = db[(size_t)i * LDA + t];
    dinv[t] = 1.0f / Lb[t][t];
    __syncthreads();
    int r = (p + 1) * 64 + blockIdx.x * 64 + t;
    if (r <= QQ) {
        float* ar = A + (size_t)r * LDA + p * 64;
        float x[64];
#pragma unroll
        for (int jj = 0; jj < 16; ++jj) {
            float4 v = ((const float4*)ar)[jj];
            x[4 * jj] = v.x; x[4 * jj + 1] = v.y; x[4 * jj + 2] = v.z; x[4 * jj + 3] = v.w;
        }
        TStep<0>::run(Lb, dinv, x);
#pragma unroll
        for (int jj = 0; jj < 16; ++jj)
            ((float4*)ar)[jj] = make_float4(x[4 * jj], x[4 * jj + 1], x[4 * jj + 2], x[4 * jj + 3]);
    }
}

// ---------------- syrk: trailing update A -= P * P^T (lower tiles only) ----------------
__global__ void k_syrk(float* __restrict__ A, int p) {
    int t0 = (p + 1) * 64;
    int r0 = t0 + blockIdx.y * 32;
    int c0 = t0 + blockIdx.x * 32;
    if (c0 > r0 + 31) return;  // uniform: tile entirely above diagonal
    __shared__ float Pr[32][65];
    __shared__ float Pc[32][65];
    int t = threadIdx.x;  // 256
    int pc0 = p * 64;
    for (int idx2 = t; idx2 < 2048; idx2 += 256) {
        int i = idx2 >> 6, k = idx2 & 63;
        int rr = r0 + i;
        Pr[i][k] = (rr <= QQ) ? A[(size_t)rr * LDA + pc0 + k] : 0.f;
        int cc = c0 + i;
        Pc[i][k] = (cc < QQ) ? A[(size_t)cc * LDA + pc0 + k] : 0.f;
    }
    __syncthreads();
    int tx = t & 31, ty = t >> 5;  // ty 0..7
    float acc[4] = {0.f, 0.f, 0.f, 0.f};
#pragma unroll 4
    for (int k = 0; k < 64; ++k) {
        float b = Pc[tx][k];
#pragma unroll
        for (int ii = 0; ii < 4; ++ii)
            acc[ii] = fmaf(Pr[ty + 8 * ii][k], b, acc[ii]);
    }
#pragma unroll
    for (int ii = 0; ii < 4; ++ii) {
        int rr = r0 + ty + 8 * ii, cc = c0 + tx;
        if (rr <= QQ && cc < QQ)
            A[(size_t)rr * LDA + cc] -= acc[ii];
    }
}

// ---------------- finalize: logdet from diag, yy from bordered row, combine ----------------
__global__ void k_final(const float* __restrict__ A, const float* __restrict__ scal,
                        const float* __restrict__ se_p, float* __restrict__ out) {
    int i = threadIdx.x;  // 1024
    float v1 = 2.0f * __logf(A[(size_t)i * LDA + i]);
    float yv = A[(size_t)QQ * LDA + i];
    float v2 = yv * yv;
    for (int o = 32; o > 0; o >>= 1) {
        v1 += __shfl_down(v1, o, 64);
        v2 += __shfl_down(v2, o, 64);
    }
    __shared__ float r1[16], r2[16];
    int lane = i & 63, wid = i >> 6;
    if (lane == 0) { r1[wid] = v1; r2[wid] = v2; }
    __syncthreads();
    if (i == 0) {
        float ld = 0.f, yy = 0.f;
        for (int k = 0; k < 16; ++k) { ld += r1[k]; yy += r2[k]; }
        float se = se_p[0], inv = 1.0f / se;
        float rr = scal[0], st = scal[1];
        float quad = rr * inv - inv * inv * (st - inv * yy);
        float logdetV = (float)NN * __logf(se) + ld;
        out[0] = 0.5f * (float)NN * 1.8378770664093453f + 0.5f * logdetV + 0.5f * quad;
    }
}

extern "C" void kernel_launch(void* const* d_in, const int* in_sizes, int n_in,
                              void* d_out, int out_size, void* d_ws, size_t ws_size,
                              hipStream_t stream) {
    const float* yt   = (const float*)d_in[0];
    const float* yp   = (const float*)d_in[1];
    const int*   idx  = (const int*)d_in[2];
    const float* dist = (const float*)d_in[3];
    const float* se   = (const float*)d_in[4];
    const float* sbs  = (const float*)d_in[5];
    float* out = (float*)d_out;

    float* W    = (float*)d_ws;
    float* A    = W;                      // 1025 x LDA
    int*   c    = (int*)(W + AF);         // 1024
    float* s    = W + AF + 1024;          // 1024
    float* scal = W + AF + 2048;          // rr, st
    float* t    = scal + 2;               // 1024
    float* w    = t + 1024;               // 1024
    float* sqc  = w + 1024;               // 1024

    // zero accumulators: c(1024 int) + s(1024 f) + scal(2 f), contiguous
    hipMemsetAsync(c, 0, (1024 + 1024 + 2) * sizeof(float), stream);

    k_stats<<<dim3(NN / 256), dim3(256), 0, stream>>>(yt, yp, idx, s, c, scal);
    k_matvec<<<dim3(QQ), dim3(256), 0, stream>>>(dist, s, c, t, w, sqc, scal, sbs);
    k_build<<<dim3(QQ + 1), dim3(256), 0, stream>>>(dist, sqc, w, A, se, sbs);

    for (int p = 0; p < 16; ++p) {
        k_potrf<<<dim3(1), dim3(256), 0, stream>>>(A, p);
        int rows = (QQ + 1) - (p + 1) * 64;
        k_trsm<<<dim3((rows + 63) / 64), dim3(64), 0, stream>>>(A, p);
        int cols = QQ - (p + 1) * 64;
        if (cols > 0) {
            dim3 g((cols + 31) / 32, (rows + 31) / 32);
            k_syrk<<<g, dim3(256), 0, stream>>>(A, p);
        }
    }
    k_final<<<dim3(1), dim3(1024), 0, stream>>>(A, scal, se, out);
}

// Round 7
// 688.360 us; speedup vs baseline: 4.0966x; 1.1578x over previous
//
#include <hip/hip_runtime.h>
#include <math.h>

#define NN 4096
#define QQ 1024
#define LDA 1032              // padded leading dim (16B-aligned rows)
#define AF (1025 * 1032)      // floats occupied by bordered matrix A (1025 rows)

// ---------------- stats: r = yt-yp; s[q] += r; c[q] += 1; rr = sum r^2 ----------------
__global__ void k_stats(const float* __restrict__ yt, const float* __restrict__ yp,
                        const int* __restrict__ idx, float* __restrict__ s,
                        int* __restrict__ c, float* __restrict__ scal) {
    int i = blockIdx.x * 256 + threadIdx.x;
    float r = yt[i] - yp[i];
    int q = idx[i];
    atomicAdd(&s[q], r);
    atomicAdd(&c[q], 1);
    float v = r * r;
    for (int o = 32; o > 0; o >>= 1) v += __shfl_down(v, o, 64);
    __shared__ float red[4];
    int lane = threadIdx.x & 63, wid = threadIdx.x >> 6;
    if (lane == 0) red[wid] = v;
    __syncthreads();
    if (threadIdx.x == 0) atomicAdd(&scal[0], red[0] + red[1] + red[2] + red[3]);
}

// ---------------- matvec: t = D s ; w = sqrt(c)*t ; sqc ; st = s.t ----------------
__global__ void k_matvec(const float* __restrict__ dist, const float* __restrict__ s,
                         const int* __restrict__ c, float* __restrict__ t,
                         float* __restrict__ w, float* __restrict__ sqc,
                         float* __restrict__ scal, const float* __restrict__ sbs) {
    int i = blockIdx.x;
    float sb0 = sbs[0];
    float inv2 = 1.0f / (2.0f * sbs[1]);
    const float* dr = dist + (size_t)i * QQ;
    float acc = 0.f;
    for (int j = threadIdx.x; j < QQ; j += 256)
        acc += __expf(-dr[j] * inv2) * s[j];
    for (int o = 32; o > 0; o >>= 1) acc += __shfl_down(acc, o, 64);
    __shared__ float red[4];
    int lane = threadIdx.x & 63, wid = threadIdx.x >> 6;
    if (lane == 0) red[wid] = acc;
    __syncthreads();
    if (threadIdx.x == 0) {
        float tot = (red[0] + red[1] + red[2] + red[3]) * sb0;
        t[i] = tot;
        float sq = sqrtf((float)c[i]);
        sqc[i] = sq;
        w[i] = sq * tot;
        atomicAdd(&scal[1], s[i] * tot);
    }
}

// ---------------- build bordered S: A[i][j] = I + inv_se*sqc_i*sqc_j*D_ij; row QQ = w ----------------
__global__ void k_build(const float* __restrict__ dist, const float* __restrict__ sqc,
                        const float* __restrict__ w, float* __restrict__ A,
                        const float* __restrict__ se_p, const float* __restrict__ sbs) {
    int i = blockIdx.x;  // 0..1024
    if (i == QQ) {
        for (int j = threadIdx.x; j < QQ; j += 256) A[(size_t)QQ * LDA + j] = w[j];
        return;
    }
    float sb0 = sbs[0];
    float inv2 = 1.0f / (2.0f * sbs[1]);
    float inv_se = 1.0f / se_p[0];
    float qi = sqc[i] * inv_se * sb0;
    const float* dr = dist + (size_t)i * QQ;
    float* ar = A + (size_t)i * LDA;
    for (int j = threadIdx.x; j < QQ; j += 256)
        ar[j] = ((i == j) ? 1.0f : 0.0f) + qi * sqc[j] * __expf(-dr[j] * inv2);
}

// ======== rank-2 register potrf of a 64x64 tile (256 threads) ========
// Thread (i = tid&63, q = tid>>6) owns x[16] = row i, cols 16q..16q+15; all
// indices compile-time (spill-proof, the R2-R4 lesson). Two columns factored
// per barrier: owner wave fixes col k+1 in-register after col k, publishes
// both as float2; others do a rank-2 update. 32 barriers instead of 64.
__device__ __forceinline__ void potrf64_run(float (&x)[16], int i, int q,
                                            float2 (&col2)[2][64]) {
#pragma unroll
    for (int qk = 0; qk < 4; ++qk) {
#pragma unroll
        for (int c2 = 0; c2 < 8; ++c2) {
            const int k = qk * 16 + 2 * c2;
            const int ck = 2 * c2;
            const int b = c2 & 1;
            if (q == qk) {                        // wave-uniform
                float xk = x[ck];
                float d0 = __shfl(xk, k, 64);     // constexpr lane -> readlane
                float rs0 = rsqrtf(d0);
                float l0 = (i == k) ? d0 * rs0 : xk * rs0;
                if (i >= k) x[ck] = l0;
                float lk1 = __shfl(l0, k + 1, 64);        // L[k+1][k]
                float x1v = fmaf(-l0, lk1, x[ck + 1]);    // col k+1 after col-k update
                float d1 = __shfl(x1v, k + 1, 64);
                float rs1 = rsqrtf(d1);
                float l1 = (i == k + 1) ? d1 * rs1 : x1v * rs1;
                if (i >= k + 1) x[ck + 1] = l1;
                col2[b][i] = make_float2(l0, l1); // i<k lanes publish garbage, never read
            }
            __syncthreads();
            if (16 * q + 15 > k + 1 && i > k) {
                float2 lp = col2[b][i];
                const float4* cp = (const float4*)(&col2[b][16 * q]);
#pragma unroll
                for (int m2 = 0; m2 < 8; ++m2) {
                    float4 v = cp[m2];            // cols 16q+2m2 (x,y), 16q+2m2+1 (z,w)
                    if (16 * q + 2 * m2 > k + 1)
                        x[2 * m2] = fmaf(-lp.x, v.x, fmaf(-lp.y, v.y, x[2 * m2]));
                    if (16 * q + 2 * m2 + 1 > k + 1)
                        x[2 * m2 + 1] = fmaf(-lp.x, v.z, fmaf(-lp.y, v.w, x[2 * m2 + 1]));
                }
            }
        }
    }
}

// ---------------- standalone potrf for panel 0 ----------------
__global__ __launch_bounds__(256) void k_potrf0(float* __restrict__ A) {
    __shared__ float2 col2[2][64];
    int tid = threadIdx.x, i = tid & 63, q = tid >> 6;
    float* row = A + (size_t)i * LDA + 16 * q;
    float x[16];
#pragma unroll
    for (int m4 = 0; m4 < 4; ++m4) {
        float4 v = ((const float4*)row)[m4];
        x[4 * m4] = v.x; x[4 * m4 + 1] = v.y; x[4 * m4 + 2] = v.z; x[4 * m4 + 3] = v.w;
    }
    potrf64_run(x, i, q, col2);
#pragma unroll
    for (int m4 = 0; m4 < 4; ++m4)
        ((float4*)row)[m4] = make_float4(x[4 * m4], x[4 * m4 + 1], x[4 * m4 + 2], x[4 * m4 + 3]);
}

// ======== template-unrolled trsm helpers ========
template<int K, int M>
struct TAcc {
    static __device__ __forceinline__ void run(const float (&Lb)[64][65], const float (&x)[64],
                                               float& a0, float& a1) {
        if constexpr (M < K)     a0 = fmaf(-Lb[K][M], x[M], a0);
        if constexpr (M + 1 < K) a1 = fmaf(-Lb[K][M + 1], x[M + 1], a1);
        if constexpr (M + 2 < K) TAcc<K, M + 2>::run(Lb, x, a0, a1);
    }
};
template<int K>
struct TStep {
    static __device__ __forceinline__ void run(const float (&Lb)[64][65], const float (&dinv)[64],
                                               float (&x)[64]) {
        if constexpr (K < 64) {
            float a0 = x[K], a1 = 0.f;
            TAcc<K, 0>::run(Lb, x, a0, a1);
            x[K] = (a0 + a1) * dinv[K];
            TStep<K + 1>::run(Lb, dinv, x);
        }
    }
};

// ---------------- trsm: rows below panel (incl. bordered w-row): X * Lpp^T = A_panel ----------------
__global__ __launch_bounds__(64, 2) void k_trsm(float* __restrict__ A, int p) {
    __shared__ float Lb[64][65];
    __shared__ float dinv[64];
    int t = threadIdx.x;  // 64 threads
    const float* db = A + (size_t)(p * 64) * (LDA + 1);
    for (int i = 0; i < 64; ++i) Lb[i][t] = db[(size_t)i * LDA + t];
    dinv[t] = 1.0f / Lb[t][t];
    __syncthreads();
    int r = (p + 1) * 64 + blockIdx.x * 64 + t;
    if (r <= QQ) {
        float* ar = A + (size_t)r * LDA + p * 64;
        float x[64];
#pragma unroll
        for (int jj = 0; jj < 16; ++jj) {
            float4 v = ((const float4*)ar)[jj];
            x[4 * jj] = v.x; x[4 * jj + 1] = v.y; x[4 * jj + 2] = v.z; x[4 * jj + 3] = v.w;
        }
        TStep<0>::run(Lb, dinv, x);
#pragma unroll
        for (int jj = 0; jj < 16; ++jj)
            ((float4*)ar)[jj] = make_float4(x[4 * jj], x[4 * jj + 1], x[4 * jj + 2], x[4 * jj + 3]);
    }
}

// ---------------- fused syrk + next-panel potrf ----------------
// 64x64 tiles, 256 threads (tx=tid&15, ty=tid>>4), micro-tile rows ty+16*ii,
// cols tx+16*jj (strided -> 2-way-max LDS banks). Block (0,0) updates the
// next panel's diagonal tile into LDS and factorizes it in-place (potrf64),
// eliminating the separate potrf dispatch per panel.
__global__ __launch_bounds__(256) void k_syrkpotrf(float* __restrict__ A, int p) {
    int t0 = (p + 1) * 64;
    int r0 = t0 + blockIdx.y * 64;
    int c0 = t0 + blockIdx.x * 64;
    if (c0 > r0) return;  // block-uniform: tile above diagonal
    bool dfuse = (blockIdx.x == 0 && blockIdx.y == 0);
    __shared__ __align__(16) float PrRaw[64 * 68];
    __shared__ __align__(16) float PcRaw[64 * 68];
    __shared__ float2 col2[2][64];
    int tid = threadIdx.x;
    int tx = tid & 15, ty = tid >> 4;
    int pc0 = p * 64;
    for (int idx2 = tid; idx2 < 1024; idx2 += 256) {
        int rr = idx2 >> 4, c4 = idx2 & 15;
        int gr = r0 + rr;
        float4 v = make_float4(0.f, 0.f, 0.f, 0.f);
        if (gr <= QQ) v = *(const float4*)(A + (size_t)gr * LDA + pc0 + 4 * c4);
        *(float4*)(PrRaw + rr * 68 + 4 * c4) = v;
        if (!dfuse) {
            float4 u = *(const float4*)(A + (size_t)(c0 + rr) * LDA + pc0 + 4 * c4);
            *(float4*)(PcRaw + rr * 68 + 4 * c4) = u;
        }
    }
    __syncthreads();
    const float* PB = dfuse ? PrRaw : PcRaw;  // diag tile: both operands same rows
    float acc[4][4];
#pragma unroll
    for (int ii = 0; ii < 4; ++ii)
#pragma unroll
        for (int jj = 0; jj < 4; ++jj) acc[ii][jj] = 0.f;
    float4 ar[4], br[4];
#pragma unroll 4
    for (int k4 = 0; k4 < 16; ++k4) {
#pragma unroll
        for (int ii = 0; ii < 4; ++ii)
            ar[ii] = *(const float4*)(PrRaw + (ty + 16 * ii) * 68 + 4 * k4);
#pragma unroll
        for (int jj = 0; jj < 4; ++jj)
            br[jj] = *(const float4*)(PB + (tx + 16 * jj) * 68 + 4 * k4);
#pragma unroll
        for (int ii = 0; ii < 4; ++ii)
#pragma unroll
            for (int jj = 0; jj < 4; ++jj) {
                acc[ii][jj] = fmaf(ar[ii].x, br[jj].x, acc[ii][jj]);
                acc[ii][jj] = fmaf(ar[ii].y, br[jj].y, acc[ii][jj]);
                acc[ii][jj] = fmaf(ar[ii].z, br[jj].z, acc[ii][jj]);
                acc[ii][jj] = fmaf(ar[ii].w, br[jj].w, acc[ii][jj]);
            }
    }
    if (!dfuse) {
#pragma unroll
        for (int ii = 0; ii < 4; ++ii) {
            int rr = r0 + ty + 16 * ii;
            if (rr <= QQ) {
#pragma unroll
                for (int jj = 0; jj < 4; ++jj) {
                    float* pa = A + (size_t)rr * LDA + c0 + tx + 16 * jj;
                    *pa -= acc[ii][jj];
                }
            }
        }
    } else {
        // updated diagonal tile -> LDS (stride-65 view of PcRaw), then factor
#pragma unroll
        for (int ii = 0; ii < 4; ++ii) {
            int lr = ty + 16 * ii;
#pragma unroll
            for (int jj = 0; jj < 4; ++jj) {
                int lc = tx + 16 * jj;
                float old = A[(size_t)(r0 + lr) * LDA + c0 + lc];
                PcRaw[lr * 65 + lc] = old - acc[ii][jj];
            }
        }
        __syncthreads();
        int i = tid & 63, q = tid >> 6;
        float x[16];
#pragma unroll
        for (int m = 0; m < 16; ++m) x[m] = PcRaw[i * 65 + 16 * q + m];
        potrf64_run(x, i, q, col2);
        float* row = A + (size_t)(r0 + i) * LDA + c0 + 16 * q;
#pragma unroll
        for (int m4 = 0; m4 < 4; ++m4)
            ((float4*)row)[m4] = make_float4(x[4 * m4], x[4 * m4 + 1],
                                             x[4 * m4 + 2], x[4 * m4 + 3]);
    }
}

// ---------------- finalize: logdet from diag, yy from bordered row, combine ----------------
__global__ void k_final(const float* __restrict__ A, const float* __restrict__ scal,
                        const float* __restrict__ se_p, float* __restrict__ out) {
    int i = threadIdx.x;  // 1024
    float v1 = 2.0f * __logf(A[(size_t)i * LDA + i]);
    float yv = A[(size_t)QQ * LDA + i];
    float v2 = yv * yv;
    for (int o = 32; o > 0; o >>= 1) {
        v1 += __shfl_down(v1, o, 64);
        v2 += __shfl_down(v2, o, 64);
    }
    __shared__ float r1[16], r2[16];
    int lane = i & 63, wid = i >> 6;
    if (lane == 0) { r1[wid] = v1; r2[wid] = v2; }
    __syncthreads();
    if (i == 0) {
        float ld = 0.f, yy = 0.f;
        for (int k = 0; k < 16; ++k) { ld += r1[k]; yy += r2[k]; }
        float se = se_p[0], inv = 1.0f / se;
        float rr = scal[0], st = scal[1];
        float quad = rr * inv - inv * inv * (st - inv * yy);
        float logdetV = (float)NN * __logf(se) + ld;
        out[0] = 0.5f * (float)NN * 1.8378770664093453f + 0.5f * logdetV + 0.5f * quad;
    }
}

extern "C" void kernel_launch(void* const* d_in, const int* in_sizes, int n_in,
                              void* d_out, int out_size, void* d_ws, size_t ws_size,
                              hipStream_t stream) {
    const float* yt   = (const float*)d_in[0];
    const float* yp   = (const float*)d_in[1];
    const int*   idx  = (const int*)d_in[2];
    const float* dist = (const float*)d_in[3];
    const float* se   = (const float*)d_in[4];
    const float* sbs  = (const float*)d_in[5];
    float* out = (float*)d_out;

    float* W    = (float*)d_ws;
    float* A    = W;                      // 1025 x LDA
    int*   c    = (int*)(W + AF);         // 1024
    float* s    = W + AF + 1024;          // 1024
    float* scal = W + AF + 2048;          // rr, st
    float* t    = scal + 2;               // 1024
    float* w    = t + 1024;               // 1024
    float* sqc  = w + 1024;               // 1024

    // zero accumulators: c(1024 int) + s(1024 f) + scal(2 f), contiguous
    hipMemsetAsync(c, 0, (1024 + 1024 + 2) * sizeof(float), stream);

    k_stats<<<dim3(NN / 256), dim3(256), 0, stream>>>(yt, yp, idx, s, c, scal);
    k_matvec<<<dim3(QQ), dim3(256), 0, stream>>>(dist, s, c, t, w, sqc, scal, sbs);
    k_build<<<dim3(QQ + 1), dim3(256), 0, stream>>>(dist, sqc, w, A, se, sbs);

    k_potrf0<<<dim3(1), dim3(256), 0, stream>>>(A);
    for (int p = 0; p < 15; ++p) {
        int rows = (QQ + 1) - (p + 1) * 64;
        k_trsm<<<dim3((rows + 63) / 64), dim3(64), 0, stream>>>(A, p);
        int ncol = (QQ - (p + 1) * 64) / 64;
        int nr = (rows + 63) / 64;
        k_syrkpotrf<<<dim3(ncol, nr), dim3(256), 0, stream>>>(A, p);
    }
    k_trsm<<<dim3(1), dim3(64), 0, stream>>>(A, 15);  // bordered w-row vs last tile
    k_final<<<dim3(1), dim3(1024), 0, stream>>>(A, scal, se, out);
}